// Round 3
// baseline (449.127 us; speedup 1.0000x reference)
//
#include <hip/hip_runtime.h>
#include <hip/hip_bf16.h>

#define N_COPIES 8   // one accumulator copy per XCD

// Pack (T, cp) per node into float2: one 8B random load per endpoint.
__global__ void __launch_bounds__(256)
pack_nodes_kernel(const float* __restrict__ T, const float* __restrict__ cp,
                  float2* __restrict__ nodes, int n) {
    int i = blockIdx.x * blockDim.x + threadIdx.x;
    if (i < n) nodes[i] = make_float2(T[i], cp[i]);
}

// Edge-parallel. Accumulator copy selected by PHYSICAL XCD id, so each copy
// is only ever RMW'd from one XCD -> all requests to an address serialize at
// that XCD's TCC channel -> workgroup-scope (cacheable, non-write-through)
// atomics are sufficient. Dirty L2 lines write back at the end-of-kernel
// release fence; the reduce kernel then sees them.
__global__ void __launch_bounds__(256)
conduction_edge_kernel(const float2* __restrict__ nodes,
                       const float* __restrict__ L,
                       const float* __restrict__ cond,
                       const float* __restrict__ A,
                       const float* __restrict__ time_step,
                       const int* __restrict__ src,
                       const int* __restrict__ dst,
                       float* __restrict__ copies,   // [N_COPIES][n_nodes]
                       int n_nodes, int n_edges) {
    int i = blockIdx.x * blockDim.x + threadIdx.x;
    if (i >= n_edges) return;

    unsigned xcd;
    asm volatile("s_getreg_b32 %0, hwreg(HW_REG_XCC_ID)" : "=s"(xcd));
    float* __restrict__ acc = copies + (size_t)(xcd & (N_COPIES - 1)) * n_nodes;

    // Streamed edge arrays: non-temporal so they don't evict the accumulator
    // working set from this XCD's L2.
    const int s = __builtin_nontemporal_load(&src[i]);
    const int d = __builtin_nontemporal_load(&dst[i]);

    const float2 ns = nodes[s];
    const float2 nd = nodes[d];
    float delta = ns.x - nd.x;              // relu(T_src - T_dst)
    if (delta <= 0.0f) return;              // E_transf == 0 exactly -> skip

    const float Li = __builtin_nontemporal_load(&L[i]);
    const float ci = __builtin_nontemporal_load(&cond[i]);
    const float Ai = __builtin_nontemporal_load(&A[i]);
    const float dt = time_step[0];

    const float x  = (delta / Li) * ci;     // > 0 here
    const float e_cond = cbrtf(x) * Ai * dt;

    const float comb = (nd.y * ns.y) / (nd.y + ns.y);
    const float max_e = delta * comb;
    const float Et = fminf(e_cond, max_e);

    __hip_atomic_fetch_add(&acc[d],  Et, __ATOMIC_RELAXED, __HIP_MEMORY_SCOPE_WORKGROUP);
    __hip_atomic_fetch_add(&acc[s], -Et, __ATOMIC_RELAXED, __HIP_MEMORY_SCOPE_WORKGROUP);
}

// Sum the per-XCD copies into the output.
__global__ void __launch_bounds__(256)
reduce_copies_kernel(const float* __restrict__ copies, float* __restrict__ out,
                     int n_nodes) {
    int i = blockIdx.x * blockDim.x + threadIdx.x;
    if (i >= n_nodes) return;
    float v = 0.0f;
#pragma unroll
    for (int r = 0; r < N_COPIES; ++r)
        v += copies[(size_t)r * n_nodes + i];
    out[i] = v;
}

// Fallback (ws too small): direct device-scope atomics into d_out.
__global__ void __launch_bounds__(256)
conduction_edge_direct(const float* __restrict__ T, const float* __restrict__ cp,
                       const float* __restrict__ L, const float* __restrict__ cond,
                       const float* __restrict__ A, const float* __restrict__ time_step,
                       const int* __restrict__ src, const int* __restrict__ dst,
                       float* __restrict__ out, int n_edges) {
    int i = blockIdx.x * blockDim.x + threadIdx.x;
    if (i >= n_edges) return;
    const int s = src[i], d = dst[i];
    float delta = T[s] - T[d];
    if (delta <= 0.0f) return;
    const float dt = time_step[0];
    const float x = (delta / L[i]) * cond[i];
    const float e_cond = cbrtf(x) * A[i] * dt;
    const float cs = cp[s], cd = cp[d];
    const float max_e = delta * (cd * cs) / (cd + cs);
    const float Et = fminf(e_cond, max_e);
    atomicAdd(&out[d],  Et);
    atomicAdd(&out[s], -Et);
}

extern "C" void kernel_launch(void* const* d_in, const int* in_sizes, int n_in,
                              void* d_out, int out_size, void* d_ws, size_t ws_size,
                              hipStream_t stream) {
    const float* T    = (const float*)d_in[0];
    const float* cp   = (const float*)d_in[1];
    const float* L    = (const float*)d_in[2];
    const float* cond = (const float*)d_in[3];
    const float* A    = (const float*)d_in[4];
    const float* ts   = (const float*)d_in[5];
    const int*   src  = (const int*)d_in[6];
    const int*   dst  = (const int*)d_in[7];
    float* out = (float*)d_out;

    const int n_nodes = in_sizes[0];
    const int n_edges = in_sizes[2];

    const int block = 256;
    const int egrid = (n_edges + block - 1) / block;
    const int ngrid = (n_nodes + block - 1) / block;

    const size_t nodes_bytes  = (size_t)n_nodes * sizeof(float2);
    const size_t copies_bytes = (size_t)N_COPIES * n_nodes * sizeof(float);

    if (ws_size >= nodes_bytes + copies_bytes) {
        float2* nodes  = (float2*)d_ws;
        float*  copies = (float*)((char*)d_ws + nodes_bytes);

        hipMemsetAsync(copies, 0, copies_bytes, stream);
        pack_nodes_kernel<<<ngrid, block, 0, stream>>>(T, cp, nodes, n_nodes);
        conduction_edge_kernel<<<egrid, block, 0, stream>>>(
            nodes, L, cond, A, ts, src, dst, copies, n_nodes, n_edges);
        reduce_copies_kernel<<<ngrid, block, 0, stream>>>(copies, out, n_nodes);
    } else {
        hipMemsetAsync(out, 0, (size_t)out_size * sizeof(float), stream);
        conduction_edge_direct<<<egrid, block, 0, stream>>>(
            T, cp, L, cond, A, ts, src, dst, out, n_edges);
    }
}

// Round 4
// 414.091 us; speedup vs baseline: 1.0846x; 1.0846x over previous
//
#include <hip/hip_runtime.h>
#include <hip/hip_bf16.h>

#define NR     8        // node ranges (passes over the edge list, concurrent)
#define LDS_R  12800    // floats per range in LDS (51.2 KB <= 64 KB static cap)
#define MAX_B  96       // max edge slices (copies replicas in ws)

// Pack (T, cp) per node into float2: one 8B random load per endpoint.
__global__ void __launch_bounds__(256)
pack_nodes_kernel(const float* __restrict__ T, const float* __restrict__ cp,
                  float2* __restrict__ nodes, int n) {
    int i = blockIdx.x * blockDim.x + threadIdx.x;
    if (i < n) nodes[i] = make_float2(T[i], cp[i]);
}

// Per-edge transfer energy (0 if delta <= 0). Pure streaming, no atomics.
__global__ void __launch_bounds__(256)
compute_et_kernel(const float2* __restrict__ nodes,
                  const float* __restrict__ L,
                  const float* __restrict__ cond,
                  const float* __restrict__ A,
                  const float* __restrict__ time_step,
                  const int* __restrict__ src,
                  const int* __restrict__ dst,
                  float* __restrict__ Et, int n_edges) {
    int i = blockIdx.x * blockDim.x + threadIdx.x;
    if (i >= n_edges) return;
    const int s = src[i], d = dst[i];
    const float2 ns = nodes[s];
    const float2 nd = nodes[d];
    const float delta = ns.x - nd.x;
    float e = 0.0f;
    if (delta > 0.0f) {
        const float dt = time_step[0];
        const float x = (delta / __builtin_nontemporal_load(&L[i]))
                        * __builtin_nontemporal_load(&cond[i]);
        const float e_cond = cbrtf(x) * __builtin_nontemporal_load(&A[i]) * dt;
        const float comb = (nd.y * ns.y) / (nd.y + ns.y);
        e = fminf(e_cond, delta * comb);
    }
    __builtin_nontemporal_store(e, &Et[i]);
}

// Block (r, b): scan edge slice b, LDS-accumulate endpoints in node range r,
// then flush to its EXCLUSIVE region copies[b][r*R .. r*R+rlen) with plain
// stores. Zero global atomics.
__global__ void __launch_bounds__(512)
accumulate_kernel(const int* __restrict__ src,
                  const int* __restrict__ dst,
                  const float* __restrict__ Et,
                  float* __restrict__ copies,   // [B][n_nodes]
                  int n_nodes, int n_edges, int R, int chunk) {
    __shared__ float lds[LDS_R];
    const int r = blockIdx.x % NR;       // node range
    const int b = blockIdx.x / NR;       // edge slice
    const int base = r * R;
    const int rlen = min(R, n_nodes - base);

    for (int j = threadIdx.x; j < rlen; j += blockDim.x) lds[j] = 0.0f;
    __syncthreads();

    const int e0 = b * chunk;
    const int e1 = min(n_edges, e0 + chunk);
    for (int i = e0 + (int)threadIdx.x; i < e1; i += (int)blockDim.x) {
        const float e = Et[i];
        if (e == 0.0f) continue;         // ~half the edges
        const int ls = src[i] - base;
        if ((unsigned)ls < (unsigned)rlen) atomicAdd(&lds[ls], -e);
        const int ld = dst[i] - base;
        if ((unsigned)ld < (unsigned)rlen) atomicAdd(&lds[ld],  e);
    }
    __syncthreads();

    float* __restrict__ cpy = copies + (size_t)b * n_nodes + base;
    for (int j = threadIdx.x; j < rlen; j += blockDim.x) cpy[j] = lds[j];
}

// out[i] = sum over slices of copies[b][i].
__global__ void __launch_bounds__(256)
reduce_copies_kernel(const float* __restrict__ copies, float* __restrict__ out,
                     int n_nodes, int B) {
    int i = blockIdx.x * blockDim.x + threadIdx.x;
    if (i >= n_nodes) return;
    float v = 0.0f;
    for (int b = 0; b < B; ++b)
        v += copies[(size_t)b * n_nodes + i];
    out[i] = v;
}

// Fallback (ws too small): direct device-scope atomics into d_out.
__global__ void __launch_bounds__(256)
conduction_edge_direct(const float* __restrict__ T, const float* __restrict__ cp,
                       const float* __restrict__ L, const float* __restrict__ cond,
                       const float* __restrict__ A, const float* __restrict__ time_step,
                       const int* __restrict__ src, const int* __restrict__ dst,
                       float* __restrict__ out, int n_edges) {
    int i = blockIdx.x * blockDim.x + threadIdx.x;
    if (i >= n_edges) return;
    const int s = src[i], d = dst[i];
    float delta = T[s] - T[d];
    if (delta <= 0.0f) return;
    const float dt = time_step[0];
    const float x = (delta / L[i]) * cond[i];
    const float e_cond = cbrtf(x) * A[i] * dt;
    const float cs = cp[s], cd = cp[d];
    const float max_e = delta * (cd * cs) / (cd + cs);
    const float Et = fminf(e_cond, max_e);
    atomicAdd(&out[d],  Et);
    atomicAdd(&out[s], -Et);
}

extern "C" void kernel_launch(void* const* d_in, const int* in_sizes, int n_in,
                              void* d_out, int out_size, void* d_ws, size_t ws_size,
                              hipStream_t stream) {
    const float* T    = (const float*)d_in[0];
    const float* cp   = (const float*)d_in[1];
    const float* L    = (const float*)d_in[2];
    const float* cond = (const float*)d_in[3];
    const float* A    = (const float*)d_in[4];
    const float* ts   = (const float*)d_in[5];
    const int*   src  = (const int*)d_in[6];
    const int*   dst  = (const int*)d_in[7];
    float* out = (float*)d_out;

    const int n_nodes = in_sizes[0];
    const int n_edges = in_sizes[2];

    const int block = 256;
    const int egrid = (n_edges + block - 1) / block;
    const int ngrid = (n_nodes + block - 1) / block;

    const size_t nodes_bytes = (size_t)n_nodes * sizeof(float2);
    const size_t et_bytes    = (size_t)n_edges * sizeof(float);
    const size_t copy_bytes  = (size_t)n_nodes * sizeof(float);

    const int R = (n_nodes + NR - 1) / NR;

    long long avail = (long long)ws_size - (long long)(nodes_bytes + et_bytes);
    int B = (avail > 0) ? (int)(avail / (long long)copy_bytes) : 0;
    if (B > MAX_B) B = MAX_B;

    if (B >= 8 && R <= LDS_R) {
        float2* nodes  = (float2*)d_ws;
        float*  Et     = (float*)((char*)d_ws + nodes_bytes);
        float*  copies = (float*)((char*)d_ws + nodes_bytes + et_bytes);

        const int chunk = (n_edges + B - 1) / B;

        pack_nodes_kernel<<<ngrid, block, 0, stream>>>(T, cp, nodes, n_nodes);
        compute_et_kernel<<<egrid, block, 0, stream>>>(
            nodes, L, cond, A, ts, src, dst, Et, n_edges);
        accumulate_kernel<<<NR * B, 512, 0, stream>>>(
            src, dst, Et, copies, n_nodes, n_edges, R, chunk);
        reduce_copies_kernel<<<ngrid, block, 0, stream>>>(copies, out, n_nodes, B);
    } else {
        hipMemsetAsync(out, 0, (size_t)out_size * sizeof(float), stream);
        conduction_edge_direct<<<egrid, block, 0, stream>>>(
            T, cp, L, cond, A, ts, src, dst, out, n_edges);
    }
}

// Round 5
// 380.491 us; speedup vs baseline: 1.1804x; 1.0883x over previous
//
#include <hip/hip_runtime.h>
#include <hip/hip_bf16.h>

#define NR     8        // node ranges (LDS accumulator tiles)
#define LDS_R  12800    // floats per range in LDS (51.2 KB -> 3 blocks/CU)
#define N_XCD  8        // MI355X XCDs; blockIdx%8 ~ XCD round-robin heuristic

// Pack (T, cp) per node into float2: one 8B random load per endpoint.
__global__ void __launch_bounds__(256)
pack_nodes_kernel(const float* __restrict__ T, const float* __restrict__ cp,
                  float2* __restrict__ nodes, int n) {
    int i = blockIdx.x * blockDim.x + threadIdx.x;
    if (i < n) nodes[i] = make_float2(T[i], cp[i]);
}

// Per-edge transfer energy (0 if delta <= 0). Pure streaming, no atomics.
// Et / src / dst are re-read 8x by accumulate -> keep them CACHEABLE
// (no nontemporal on src/dst/Et; NT only on L/cond/A which die here).
__global__ void __launch_bounds__(256)
compute_et_kernel(const float2* __restrict__ nodes,
                  const float* __restrict__ L,
                  const float* __restrict__ cond,
                  const float* __restrict__ A,
                  const float* __restrict__ time_step,
                  const int* __restrict__ src,
                  const int* __restrict__ dst,
                  float* __restrict__ Et, int n_edges) {
    int i = blockIdx.x * blockDim.x + threadIdx.x;
    if (i >= n_edges) return;
    const int s = src[i], d = dst[i];
    const float2 ns = nodes[s];
    const float2 nd = nodes[d];
    const float delta = ns.x - nd.x;
    float e = 0.0f;
    if (delta > 0.0f) {
        const float dt = time_step[0];
        const float x = (delta / __builtin_nontemporal_load(&L[i]))
                        * __builtin_nontemporal_load(&cond[i]);
        const float e_cond = cbrtf(x) * __builtin_nontemporal_load(&A[i]) * dt;
        const float comb = (nd.y * ns.y) / (nd.y + ns.y);
        e = fminf(e_cond, delta * comb);
    }
    Et[i] = e;   // cacheable store: accumulate re-reads this 8x
}

// Block layout (XCD-swizzled): xcd = blockIdx%8, j = blockIdx/8,
// r = j%NR (node range), slice = xcd*S + j/NR. All 8 range-blocks of a
// slice share one XCD -> the slice's (src,dst,Et) chunk is HBM-fetched once
// and re-served from that XCD's 4MB L2. Grid = 8*S*NR = one residency wave.
__global__ void __launch_bounds__(512)
accumulate_kernel(const int* __restrict__ src,
                  const int* __restrict__ dst,
                  const float* __restrict__ Et,
                  float* __restrict__ copies,   // [B][n_nodes]
                  int n_nodes, int n_edges, int R, int chunk, int S) {
    __shared__ float lds[LDS_R];
    const int xcd = blockIdx.x % N_XCD;
    const int j   = blockIdx.x / N_XCD;
    const int r   = j % NR;
    const int b   = xcd * S + j / NR;    // edge slice, pinned to this XCD
    const int base = r * R;
    const int rlen = min(R, n_nodes - base);

    for (int t = threadIdx.x; t < rlen; t += blockDim.x) lds[t] = 0.0f;
    __syncthreads();

    const int e0 = b * chunk;
    const int e1 = min(n_edges, e0 + chunk);
    for (int i = e0 + (int)threadIdx.x; i < e1; i += (int)blockDim.x) {
        const float e = Et[i];
        if (e == 0.0f) continue;         // ~half the edges
        const int ls = src[i] - base;
        if ((unsigned)ls < (unsigned)rlen) atomicAdd(&lds[ls], -e);
        const int ld = dst[i] - base;
        if ((unsigned)ld < (unsigned)rlen) atomicAdd(&lds[ld],  e);
    }
    __syncthreads();

    // Exclusive region of copies[b]: plain coalesced stores, no atomics.
    float* __restrict__ cpy = copies + (size_t)b * n_nodes + base;
    for (int t = threadIdx.x; t < rlen; t += blockDim.x) cpy[t] = lds[t];
}

// out[i] = sum over slices of copies[b][i].
__global__ void __launch_bounds__(256)
reduce_copies_kernel(const float* __restrict__ copies, float* __restrict__ out,
                     int n_nodes, int B) {
    int i = blockIdx.x * blockDim.x + threadIdx.x;
    if (i >= n_nodes) return;
    float v = 0.0f;
    for (int b = 0; b < B; ++b)
        v += copies[(size_t)b * n_nodes + i];
    out[i] = v;
}

// Fallback (ws too small): direct device-scope atomics into d_out.
__global__ void __launch_bounds__(256)
conduction_edge_direct(const float* __restrict__ T, const float* __restrict__ cp,
                       const float* __restrict__ L, const float* __restrict__ cond,
                       const float* __restrict__ A, const float* __restrict__ time_step,
                       const int* __restrict__ src, const int* __restrict__ dst,
                       float* __restrict__ out, int n_edges) {
    int i = blockIdx.x * blockDim.x + threadIdx.x;
    if (i >= n_edges) return;
    const int s = src[i], d = dst[i];
    float delta = T[s] - T[d];
    if (delta <= 0.0f) return;
    const float dt = time_step[0];
    const float x = (delta / L[i]) * cond[i];
    const float e_cond = cbrtf(x) * A[i] * dt;
    const float cs = cp[s], cd = cp[d];
    const float max_e = delta * (cd * cs) / (cd + cs);
    const float Et = fminf(e_cond, max_e);
    atomicAdd(&out[d],  Et);
    atomicAdd(&out[s], -Et);
}

extern "C" void kernel_launch(void* const* d_in, const int* in_sizes, int n_in,
                              void* d_out, int out_size, void* d_ws, size_t ws_size,
                              hipStream_t stream) {
    const float* T    = (const float*)d_in[0];
    const float* cp   = (const float*)d_in[1];
    const float* L    = (const float*)d_in[2];
    const float* cond = (const float*)d_in[3];
    const float* A    = (const float*)d_in[4];
    const float* ts   = (const float*)d_in[5];
    const int*   src  = (const int*)d_in[6];
    const int*   dst  = (const int*)d_in[7];
    float* out = (float*)d_out;

    const int n_nodes = in_sizes[0];
    const int n_edges = in_sizes[2];

    const int block = 256;
    const int egrid = (n_edges + block - 1) / block;
    const int ngrid = (n_nodes + block - 1) / block;

    const size_t nodes_bytes = (size_t)n_nodes * sizeof(float2);
    const size_t et_bytes    = (size_t)n_edges * sizeof(float);
    const size_t copy_bytes  = (size_t)n_nodes * sizeof(float);

    const int R = (n_nodes + NR - 1) / NR;

    long long avail = (long long)ws_size - (long long)(nodes_bytes + et_bytes);
    int B = (avail > 0) ? (int)(avail / (long long)copy_bytes) : 0;
    if (B > 96) B = 96;          // 8 XCD * 12 slices * 8 ranges = 768 = 3 blk/CU
    B &= ~(N_XCD - 1);           // need multiple of 8 for the XCD swizzle

    if (B >= N_XCD && R <= LDS_R) {
        float2* nodes  = (float2*)d_ws;
        float*  Et     = (float*)((char*)d_ws + nodes_bytes);
        float*  copies = (float*)((char*)d_ws + nodes_bytes + et_bytes);

        const int S = B / N_XCD;             // slices per XCD
        const int chunk = (n_edges + B - 1) / B;

        pack_nodes_kernel<<<ngrid, block, 0, stream>>>(T, cp, nodes, n_nodes);
        compute_et_kernel<<<egrid, block, 0, stream>>>(
            nodes, L, cond, A, ts, src, dst, Et, n_edges);
        accumulate_kernel<<<NR * B, 512, 0, stream>>>(
            src, dst, Et, copies, n_nodes, n_edges, R, chunk, S);
        reduce_copies_kernel<<<ngrid, block, 0, stream>>>(copies, out, n_nodes, B);
    } else {
        hipMemsetAsync(out, 0, (size_t)out_size * sizeof(float), stream);
        conduction_edge_direct<<<egrid, block, 0, stream>>>(
            T, cp, L, cond, A, ts, src, dst, out, n_edges);
    }
}

// Round 7
// 265.325 us; speedup vs baseline: 1.6927x; 1.4341x over previous
//
#include <hip/hip_runtime.h>
#include <hip/hip_bf16.h>

#define NR     8        // node ranges (LDS accumulator tiles)
#define LDS_R  12800    // floats per range in LDS (51.2 KB -> 3 blocks/CU)
#define N_XCD  8        // MI355X XCDs; blockIdx%8 ~ XCD round-robin heuristic

typedef float vfloat4 __attribute__((ext_vector_type(4)));  // NT-load compatible

// Pack (T, cp) per node into float2: one 8B random load per endpoint.
__global__ void __launch_bounds__(256)
pack_nodes_kernel(const float* __restrict__ T, const float* __restrict__ cp,
                  float2* __restrict__ nodes, int n) {
    int i = blockIdx.x * blockDim.x + threadIdx.x;
    if (i < n) nodes[i] = make_float2(T[i], cp[i]);
}

__device__ __forceinline__ float edge_e(float2 ns, float2 nd, float Li,
                                        float ci, float Ai, float dt) {
    const float delta = ns.x - nd.x;
    if (delta <= 0.0f) return 0.0f;
    const float x = (delta / Li) * ci;
    const float ec = cbrtf(x) * Ai * dt;
    const float comb = (nd.y * ns.y) / (nd.y + ns.y);
    return fminf(ec, delta * comb);
}

// Per-edge transfer energy, 4 edges/thread: all vector loads + 8 node
// gathers issued independently -> one latency chain covers 4 edges.
__global__ void __launch_bounds__(256)
compute_et_kernel(const float2* __restrict__ nodes,
                  const float* __restrict__ L,
                  const float* __restrict__ cond,
                  const float* __restrict__ A,
                  const float* __restrict__ time_step,
                  const int* __restrict__ src,
                  const int* __restrict__ dst,
                  float* __restrict__ Et, int n_edges) {
    const int k = blockIdx.x * blockDim.x + threadIdx.x;   // vec4 index
    const int nvec = n_edges >> 2;
    const float dt = time_step[0];
    if (k < nvec) {
        const int4    s  = ((const int4*)src)[k];
        const int4    d  = ((const int4*)dst)[k];
        const vfloat4 Lv = __builtin_nontemporal_load(&((const vfloat4*)L)[k]);
        const vfloat4 cv = __builtin_nontemporal_load(&((const vfloat4*)cond)[k]);
        const vfloat4 Av = __builtin_nontemporal_load(&((const vfloat4*)A)[k]);
        // 8 independent gathers
        const float2 ns0 = nodes[s.x], ns1 = nodes[s.y], ns2 = nodes[s.z], ns3 = nodes[s.w];
        const float2 nd0 = nodes[d.x], nd1 = nodes[d.y], nd2 = nodes[d.z], nd3 = nodes[d.w];
        vfloat4 e;
        e.x = edge_e(ns0, nd0, Lv.x, cv.x, Av.x, dt);
        e.y = edge_e(ns1, nd1, Lv.y, cv.y, Av.y, dt);
        e.z = edge_e(ns2, nd2, Lv.z, cv.z, Av.z, dt);
        e.w = edge_e(ns3, nd3, Lv.w, cv.w, Av.w, dt);
        ((vfloat4*)Et)[k] = e;             // cacheable: re-read 8x downstream
    } else if (k == nvec) {                // scalar tail (n_edges % 4)
        for (int i = nvec << 2; i < n_edges; ++i) {
            Et[i] = edge_e(nodes[src[i]], nodes[dst[i]], L[i], cond[i], A[i], dt);
        }
    }
}

// Block layout (XCD-swizzled): xcd = blockIdx%8, j = blockIdx/8,
// r = j%NR (node range), slice = xcd*S + j/NR. All 8 range-blocks of a slice
// share one XCD -> chunk HBM-fetched once, re-served from 4MB local L2.
// Scan is int4/float4 vectorized: 12 edges per 3 independent loads.
__global__ void __launch_bounds__(512)
accumulate_kernel(const int* __restrict__ src,
                  const int* __restrict__ dst,
                  const float* __restrict__ Et,
                  float* __restrict__ copies,   // [B][n_nodes]
                  int n_nodes, int n_edges, int R, int chunk, int S) {
    __shared__ float lds[LDS_R];
    const int xcd = blockIdx.x % N_XCD;
    const int j   = blockIdx.x / N_XCD;
    const int r   = j % NR;
    const int b   = xcd * S + j / NR;    // edge slice, pinned to this XCD
    const int base = r * R;
    const int rlen = min(R, n_nodes - base);

    for (int t = threadIdx.x; t < rlen; t += blockDim.x) lds[t] = 0.0f;
    __syncthreads();

    const int e0 = b * chunk;            // chunk % 2048 == 0 -> 16B aligned
    const int e1 = min(n_edges, e0 + chunk);
    if (e0 < e1) {
        const int nvec = (e1 - e0) >> 2;
        const int4*    s4 = (const int4*)(src + e0);
        const int4*    d4 = (const int4*)(dst + e0);
        const vfloat4* q4 = (const vfloat4*)(Et + e0);
        for (int k = threadIdx.x; k < nvec; k += blockDim.x) {
            const vfloat4 e = q4[k];
            const int4    s = s4[k];
            const int4    d = d4[k];
            if (e.x != 0.0f) {
                const int ls = s.x - base; if ((unsigned)ls < (unsigned)rlen) atomicAdd(&lds[ls], -e.x);
                const int ld = d.x - base; if ((unsigned)ld < (unsigned)rlen) atomicAdd(&lds[ld],  e.x);
            }
            if (e.y != 0.0f) {
                const int ls = s.y - base; if ((unsigned)ls < (unsigned)rlen) atomicAdd(&lds[ls], -e.y);
                const int ld = d.y - base; if ((unsigned)ld < (unsigned)rlen) atomicAdd(&lds[ld],  e.y);
            }
            if (e.z != 0.0f) {
                const int ls = s.z - base; if ((unsigned)ls < (unsigned)rlen) atomicAdd(&lds[ls], -e.z);
                const int ld = d.z - base; if ((unsigned)ld < (unsigned)rlen) atomicAdd(&lds[ld],  e.z);
            }
            if (e.w != 0.0f) {
                const int ls = s.w - base; if ((unsigned)ls < (unsigned)rlen) atomicAdd(&lds[ls], -e.w);
                const int ld = d.w - base; if ((unsigned)ld < (unsigned)rlen) atomicAdd(&lds[ld],  e.w);
            }
        }
        // scalar tail
        for (int i = e0 + (nvec << 2) + (int)threadIdx.x; i < e1; i += (int)blockDim.x) {
            const float e = Et[i];
            if (e == 0.0f) continue;
            const int ls = src[i] - base; if ((unsigned)ls < (unsigned)rlen) atomicAdd(&lds[ls], -e);
            const int ld = dst[i] - base; if ((unsigned)ld < (unsigned)rlen) atomicAdd(&lds[ld],  e);
        }
    }
    __syncthreads();

    // Exclusive region of copies[b]: plain coalesced stores, no atomics.
    float* __restrict__ cpy = copies + (size_t)b * n_nodes + base;
    for (int t = threadIdx.x; t < rlen; t += blockDim.x) cpy[t] = lds[t];
}

// out[i..i+3] = sum over slices of copies[b][i..i+3], float4-vectorized.
__global__ void __launch_bounds__(256)
reduce_copies_kernel(const float* __restrict__ copies, float* __restrict__ out,
                     int n_nodes, int B) {
    const int k = blockIdx.x * blockDim.x + threadIdx.x;
    const int nvec = n_nodes >> 2;
    if (k < nvec) {
        vfloat4 v = {0.f, 0.f, 0.f, 0.f};
        for (int b = 0; b < B; ++b) {
            const vfloat4 c = ((const vfloat4*)(copies + (size_t)b * n_nodes))[k];
            v += c;
        }
        ((vfloat4*)out)[k] = v;
    } else if (k == nvec) {
        for (int i = nvec << 2; i < n_nodes; ++i) {
            float v = 0.0f;
            for (int b = 0; b < B; ++b) v += copies[(size_t)b * n_nodes + i];
            out[i] = v;
        }
    }
}

// Fallback (ws too small): direct device-scope atomics into d_out.
__global__ void __launch_bounds__(256)
conduction_edge_direct(const float* __restrict__ T, const float* __restrict__ cp,
                       const float* __restrict__ L, const float* __restrict__ cond,
                       const float* __restrict__ A, const float* __restrict__ time_step,
                       const int* __restrict__ src, const int* __restrict__ dst,
                       float* __restrict__ out, int n_edges) {
    int i = blockIdx.x * blockDim.x + threadIdx.x;
    if (i >= n_edges) return;
    const int s = src[i], d = dst[i];
    float delta = T[s] - T[d];
    if (delta <= 0.0f) return;
    const float dt = time_step[0];
    const float x = (delta / L[i]) * cond[i];
    const float e_cond = cbrtf(x) * A[i] * dt;
    const float cs = cp[s], cd = cp[d];
    const float max_e = delta * (cd * cs) / (cd + cs);
    const float Et = fminf(e_cond, max_e);
    atomicAdd(&out[d],  Et);
    atomicAdd(&out[s], -Et);
}

extern "C" void kernel_launch(void* const* d_in, const int* in_sizes, int n_in,
                              void* d_out, int out_size, void* d_ws, size_t ws_size,
                              hipStream_t stream) {
    const float* T    = (const float*)d_in[0];
    const float* cp   = (const float*)d_in[1];
    const float* L    = (const float*)d_in[2];
    const float* cond = (const float*)d_in[3];
    const float* A    = (const float*)d_in[4];
    const float* ts   = (const float*)d_in[5];
    const int*   src  = (const int*)d_in[6];
    const int*   dst  = (const int*)d_in[7];
    float* out = (float*)d_out;

    const int n_nodes = in_sizes[0];
    const int n_edges = in_sizes[2];

    const int block = 256;
    const int ngrid = (n_nodes + block - 1) / block;

    const size_t nodes_bytes = (size_t)n_nodes * sizeof(float2);
    const size_t et_bytes    = ((size_t)n_edges + 4) * sizeof(float);
    const size_t copy_bytes  = (size_t)n_nodes * sizeof(float);

    const int R = (n_nodes + NR - 1) / NR;

    long long avail = (long long)ws_size - (long long)(nodes_bytes + et_bytes);
    int B = (avail > 0) ? (int)(avail / (long long)copy_bytes) : 0;
    if (B > 96) B = 96;          // 8 XCD * 12 slices * 8 ranges = 768 = 3 blk/CU
    B &= ~(N_XCD - 1);           // multiple of 8 for the XCD swizzle

    if (B >= N_XCD && R <= LDS_R) {
        float2* nodes  = (float2*)d_ws;
        float*  Et     = (float*)((char*)d_ws + nodes_bytes);
        float*  copies = (float*)((char*)d_ws + nodes_bytes + et_bytes);

        const int S = B / N_XCD;             // slices per XCD
        // chunk: multiple of 2048 so every slice start is int4-aligned
        int chunk = (n_edges + B - 1) / B;
        chunk = (chunk + 2047) & ~2047;

        const int et_grid = ((n_edges >> 2) + 1 + block - 1) / block;

        pack_nodes_kernel<<<ngrid, block, 0, stream>>>(T, cp, nodes, n_nodes);
        compute_et_kernel<<<et_grid, block, 0, stream>>>(
            nodes, L, cond, A, ts, src, dst, Et, n_edges);
        accumulate_kernel<<<NR * B, 512, 0, stream>>>(
            src, dst, Et, copies, n_nodes, n_edges, R, chunk, S);
        const int rgrid = ((n_nodes >> 2) + 1 + block - 1) / block;
        reduce_copies_kernel<<<rgrid, block, 0, stream>>>(copies, out, n_nodes, B);
    } else {
        (void)hipMemsetAsync(out, 0, (size_t)out_size * sizeof(float), stream);
        const int egrid = (n_edges + block - 1) / block;
        conduction_edge_direct<<<egrid, block, 0, stream>>>(
            T, cp, L, cond, A, ts, src, dst, out, n_edges);
    }
}